// Round 2
// baseline (14026.933 us; speedup 1.0000x reference)
//
#include <hip/hip_runtime.h>

#define SEQ  4096
#define NB   64
#define NI   64
#define NH   256

typedef short  bf16x8 __attribute__((ext_vector_type(8)));
typedef short  bf16x2 __attribute__((ext_vector_type(2)));
typedef float  f32x4  __attribute__((ext_vector_type(4)));

__device__ __forceinline__ unsigned short f2bf(float f) {
    union { float f; unsigned u; } v; v.f = f;
    return (unsigned short)((v.u + 0x7fffu + ((v.u >> 16) & 1u)) >> 16);
}
__device__ __forceinline__ float fast_rcp(float x) { return __builtin_amdgcn_rcpf(x); }
__device__ __forceinline__ float sigm(float x) { return fast_rcp(1.f + __expf(-x)); }
__device__ __forceinline__ float tanh_(float x) {
    x = fminf(15.f, fmaxf(-15.f, x));
    float e = __expf(2.f * x);
    return (e - 1.f) * fast_rcp(e + 1.f);
}
__device__ __forceinline__ f32x4 mfma16(bf16x8 a, bf16x8 b, f32x4 c) {
    return __builtin_amdgcn_mfma_f32_16x16x32_bf16(a, b, c, 0, 0, 0);
}
// load 8 consecutive fp32, round to bf16, pack as one MFMA fragment
__device__ __forceinline__ bf16x8 ldfrag(const float* p) {
    float4 a = *(const float4*)p;
    float4 b = *(const float4*)(p + 4);
    bf16x8 r;
    r[0] = (short)f2bf(a.x); r[1] = (short)f2bf(a.y);
    r[2] = (short)f2bf(a.z); r[3] = (short)f2bf(a.w);
    r[4] = (short)f2bf(b.x); r[5] = (short)f2bf(b.y);
    r[6] = (short)f2bf(b.z); r[7] = (short)f2bf(b.w);
    return r;
}

// One block = 16 batch elements, 8 waves. Wave w owns j-blocks {2w, 2w+1}
// (32 hidden units) for all 3 gates. Augmented operand per batch row:
// [h(256) | x(64)], K=320 = 10 chunks of 32. r/z weight tiles are
// [W_hh | W_ih] (10 frags, VGPR); n-gate: W_hh frags in LDS (r gates the
// hidden side separately), W_ih n-frags in VGPR.
// A-frag addr (b,k): (k>>5)*512 + (((k>>3)&3)*16 + b)*8 + (k&7)   [shorts]
// MFMA 16x16x32 C/D: col = lane&15, row = (lane>>4)*4 + reg.
__global__ __launch_bounds__(512, 2) void gru_fused(
        const float* __restrict__ x,
        const float* __restrict__ w_ih,
        const float* __restrict__ w_hh,
        const float* __restrict__ b_ih,
        const float* __restrict__ b_hh,
        const float* __restrict__ fc_w,
        const float* __restrict__ fc_b,
        float* __restrict__ out)
{
    // static LDS: 131072 + 20480 + 1024 = 152576 B (gfx950 max 163840)
    __shared__ short wlds[65536];     // n-gate W_hh frags: 128 rows x 512 shorts
    __shared__ short abuf[10240];     // [h|x] staging, 2 x 5120 shorts (dbuf)
    __shared__ float fcred[256];      // fc partials, 2 x 8 waves x 16 batch

    const int tid   = threadIdx.x;
    const int wv    = tid >> 6;
    const int lane  = tid & 63;
    const int nn    = lane & 15;
    const int q     = lane >> 4;
    const int bbase = blockIdx.x * 16;

    // ---- one-time: weights into regs / LDS ----
    bf16x8 wrz[4][10];               // tiles 0,1 = r; 2,3 = z (augmented K=320)
    #pragma unroll
    for (int t = 0; t < 4; ++t) {
        const int row = (t >> 1) * NH + (2 * wv + (t & 1)) * 16 + nn;
        #pragma unroll
        for (int c = 0; c < 8; ++c)
            wrz[t][c] = ldfrag(w_hh + row * NH + c * 32 + q * 8);
        #pragma unroll
        for (int c = 8; c < 10; ++c)
            wrz[t][c] = ldfrag(w_ih + row * NI + (c - 8) * 32 + q * 8);
    }
    bf16x8 wnx[2][2];                // n-gate W_ih frags
    #pragma unroll
    for (int tt = 0; tt < 2; ++tt) {
        const int row = 2 * NH + (2 * wv + tt) * 16 + nn;
        #pragma unroll
        for (int c = 0; c < 2; ++c)
            wnx[tt][c] = ldfrag(w_ih + row * NI + c * 32 + q * 8);
    }
    #pragma unroll
    for (int tt = 0; tt < 2; ++tt) {  // n-gate W_hh -> LDS
        const int row = 2 * NH + (2 * wv + tt) * 16 + nn;
        #pragma unroll
        for (int c = 0; c < 8; ++c) {
            bf16x8 f = ldfrag(w_hh + row * NH + c * 32 + q * 8);
            *(bf16x8*)(wlds + (wv * 16 + tt * 8 + c) * 512 + lane * 8) = f;
        }
    }
    float bm[4], bx[2], bh[2], fcw[2];
    #pragma unroll
    for (int t = 0; t < 4; ++t) {
        const int row = (t >> 1) * NH + (2 * wv + (t & 1)) * 16 + nn;
        bm[t] = b_ih[row] + b_hh[row];
    }
    #pragma unroll
    for (int tt = 0; tt < 2; ++tt) {
        const int row = 2 * NH + (2 * wv + tt) * 16 + nn;
        bx[tt] = b_ih[row];
        bh[tt] = b_hh[row];
        fcw[tt] = fc_w[(2 * wv + tt) * 16 + nn];
    }
    const float fcb = fc_b[0];

    ((int4*)abuf)[tid] = make_int4(0, 0, 0, 0);   // h_0 = 0 (chunks 0..7 of buf 0)
    {   // stage x_0 into buf 0 chunks 8,9
        const int f = 2 * tid, b = f >> 6, i = f & 63;
        float2 v = *(const float2*)(x + (size_t)bbase * NI + f);
        bf16x2 s; s[0] = (short)f2bf(v.x); s[1] = (short)f2bf(v.y);
        *(bf16x2*)(abuf + (8 + (i >> 5)) * 512 + (((i >> 3) & 3) * 16 + b) * 8 + (i & 7)) = s;
    }
    f32x4 hp0 = 0, hp1 = 0;           // fp32 h state for this lane's (b,j) cells
    const float* xp = x + (size_t)(NB + bbase) * NI + 2 * tid;  // x_{t+1} stream
    float* op = out + bbase + lane;                             // out stream
    __syncthreads();

    for (int t = 0; t < SEQ; ++t) {
        const int cur = t & 1, nxt = cur ^ 1;
        const bool hasnext = (t + 1 < SEQ);
        float2 xv = make_float2(0.f, 0.f);
        if (hasnext) { xv = *(const float2*)xp; xp += NB * NI; }

        f32x4 a0 = 0, a1 = 0, a2 = 0, a3 = 0, an0 = 0, an1 = 0, ax0 = 0, ax1 = 0;
        const short* ab = abuf + cur * 5120;
        #pragma unroll
        for (int c = 0; c < 8; ++c) {
            bf16x8 av = *(const bf16x8*)(ab + c * 512 + lane * 8);
            a0 = mfma16(av, wrz[0][c], a0);
            a1 = mfma16(av, wrz[1][c], a1);
            a2 = mfma16(av, wrz[2][c], a2);
            a3 = mfma16(av, wrz[3][c], a3);
            bf16x8 w4 = *(const bf16x8*)(wlds + (wv * 16 + c) * 512 + lane * 8);
            an0 = mfma16(av, w4, an0);
            bf16x8 w5 = *(const bf16x8*)(wlds + (wv * 16 + 8 + c) * 512 + lane * 8);
            an1 = mfma16(av, w5, an1);
        }
        #pragma unroll
        for (int c = 8; c < 10; ++c) {
            bf16x8 av = *(const bf16x8*)(ab + c * 512 + lane * 8);
            a0 = mfma16(av, wrz[0][c], a0);
            a1 = mfma16(av, wrz[1][c], a1);
            a2 = mfma16(av, wrz[2][c], a2);
            a3 = mfma16(av, wrz[3][c], a3);
            ax0 = mfma16(av, wnx[0][c - 8], ax0);
            ax1 = mfma16(av, wnx[1][c - 8], ax1);
        }

        short* hbn = abuf + nxt * 5120;
        f32x4 pf4 = 0;
        {   // j-block 0
            const int j = (2 * wv) * 16 + nn;
            const int koff = (j >> 5) * 512 + ((j >> 3) & 3) * 128 + (j & 7);
            f32x4 hnew;
            #pragma unroll
            for (int m = 0; m < 4; ++m) {
                float r_ = sigm(a0[m] + bm[0]);
                float z_ = sigm(a2[m] + bm[2]);
                float n_ = tanh_(ax0[m] + bx[0] + r_ * (an0[m] + bh[0]));
                hnew[m] = (1.f - z_) * n_ + z_ * hp0[m];
            }
            hp0 = hnew;
            #pragma unroll
            for (int m = 0; m < 4; ++m)
                hbn[koff + (q * 4 + m) * 8] = (short)f2bf(hnew[m]);
            pf4 += hnew * fcw[0];
        }
        {   // j-block 1
            const int j = (2 * wv + 1) * 16 + nn;
            const int koff = (j >> 5) * 512 + ((j >> 3) & 3) * 128 + (j & 7);
            f32x4 hnew;
            #pragma unroll
            for (int m = 0; m < 4; ++m) {
                float r_ = sigm(a1[m] + bm[1]);
                float z_ = sigm(a3[m] + bm[3]);
                float n_ = tanh_(ax1[m] + bx[1] + r_ * (an1[m] + bh[1]));
                hnew[m] = (1.f - z_) * n_ + z_ * hp1[m];
            }
            hp1 = hnew;
            #pragma unroll
            for (int m = 0; m < 4; ++m)
                hbn[koff + (q * 4 + m) * 8] = (short)f2bf(hnew[m]);
            pf4 += hnew * fcw[1];
        }

        if (hasnext) {   // stage x_{t+1} into buf nxt chunks 8,9
            const int f = 2 * tid, b = f >> 6, i = f & 63;
            bf16x2 s; s[0] = (short)f2bf(xv.x); s[1] = (short)f2bf(xv.y);
            *(bf16x2*)(abuf + nxt * 5120 + (8 + (i >> 5)) * 512 +
                       (((i >> 3) & 3) * 16 + b) * 8 + (i & 7)) = s;
        }
        // fused FC: reduce h_new * fc_w across the 16 lanes of each quad group
        #pragma unroll
        for (int d = 1; d < 16; d <<= 1) {
            pf4[0] += __shfl_xor(pf4[0], d);
            pf4[1] += __shfl_xor(pf4[1], d);
            pf4[2] += __shfl_xor(pf4[2], d);
            pf4[3] += __shfl_xor(pf4[3], d);
        }
        if (nn == 0)
            *(f32x4*)(fcred + cur * 128 + wv * 16 + q * 4) = pf4;
        __syncthreads();   // barrier A: h', x', fc partials visible
        if (wv == 0 && lane < 16) {
            float s = fcb;
            #pragma unroll
            for (int ww = 0; ww < 8; ++ww)
                s += fcred[cur * 128 + ww * 16 + lane];
            *op = s;
        }
        if (wv == 0) op += NB;
        __syncthreads();   // barrier B: no wave re-enters before out/fcred read done
    }
}

extern "C" void kernel_launch(void* const* d_in, const int* in_sizes, int n_in,
                              void* d_out, int out_size, void* d_ws, size_t ws_size,
                              hipStream_t stream) {
    (void)in_sizes; (void)n_in; (void)d_ws; (void)ws_size; (void)out_size;
    gru_fused<<<dim3(4), dim3(512), 0, stream>>>(
        (const float*)d_in[0], (const float*)d_in[1], (const float*)d_in[2],
        (const float*)d_in[3], (const float*)d_in[4], (const float*)d_in[5],
        (const float*)d_in[6], (float*)d_out);
}

// Round 3
// 7966.043 us; speedup vs baseline: 1.7608x; 1.7608x over previous
//
#include <hip/hip_runtime.h>

#define SEQ  4096
#define NB   64
#define NI   64
#define NH   256

typedef short  bf16x8 __attribute__((ext_vector_type(8)));
typedef short  bf16x4 __attribute__((ext_vector_type(4)));
typedef short  bf16x2 __attribute__((ext_vector_type(2)));
typedef float  f32x4  __attribute__((ext_vector_type(4)));

__device__ __forceinline__ unsigned short f2bf(float f) {
    union { float f; unsigned u; } v; v.f = f;
    return (unsigned short)((v.u + 0x7fffu + ((v.u >> 16) & 1u)) >> 16);
}
__device__ __forceinline__ float bflo(int p) {   // low bf16 of a dword -> f32
    union { int i; float f; } u; u.i = p << 16; return u.f;
}
__device__ __forceinline__ float bfhi(int p) {   // high bf16 of a dword -> f32
    union { int i; float f; } u; u.i = p & 0xffff0000; return u.f;
}
__device__ __forceinline__ float fast_rcp(float x) { return __builtin_amdgcn_rcpf(x); }
__device__ __forceinline__ float sigm(float x) { return fast_rcp(1.f + __expf(-x)); }
__device__ __forceinline__ float tanh_(float x) {
    x = fminf(15.f, fmaxf(-15.f, x));
    float e = __expf(2.f * x);
    return (e - 1.f) * fast_rcp(e + 1.f);
}
__device__ __forceinline__ f32x4 mfma16(bf16x8 a, bf16x8 b, f32x4 c) {
    return __builtin_amdgcn_mfma_f32_16x16x32_bf16(a, b, c, 0, 0, 0);
}
__device__ __forceinline__ bf16x8 ldfrag(const float* p) {
    float4 a = *(const float4*)p;
    float4 b = *(const float4*)(p + 4);
    bf16x8 r;
    r[0] = (short)f2bf(a.x); r[1] = (short)f2bf(a.y);
    r[2] = (short)f2bf(a.z); r[3] = (short)f2bf(a.w);
    r[4] = (short)f2bf(b.x); r[5] = (short)f2bf(b.y);
    r[6] = (short)f2bf(b.z); r[7] = (short)f2bf(b.w);
    return r;
}

// ============ precompute: xg[t][b][g] = x.W_ih^T + b_ih, permuted layout ====
// xg layout (bf16 shorts): entry e = (((tl*4 + bc)*16 + wsub)*64 + lane)*12
//   + slot*4 + m   where slot 0/1/2 = r/z/n gate, wsub = j-block, lane=(nn,q),
//   m = batch-row reg.  Exactly what gru_rec's lane (nn,q) of wave wsub needs.
__global__ __launch_bounds__(512) void xg_pre(
        const float* __restrict__ x, const float* __restrict__ w_ih,
        const float* __restrict__ b_ih, short* __restrict__ xg,
        int t0, int ns)
{
    __shared__ short wihs[49152];   // 48 gate-tiles x 2 K-chunks x 512 shorts
    __shared__ short axs[1024];     // one 16-row x 64-K A tile

    const int tid = threadIdx.x, wv = tid >> 6, lane = tid & 63;
    const int nn = lane & 15, q = lane >> 4;

    float bb[6];
    #pragma unroll
    for (int i = 0; i < 6; ++i) {               // wave wv stages jb = wv + 8i
        const int jb = wv + 8 * i;
        #pragma unroll
        for (int c = 0; c < 2; ++c) {
            bf16x8 f = ldfrag(w_ih + (jb * 16 + nn) * NI + c * 32 + q * 8);
            *(bf16x8*)(wihs + (jb * 2 + c) * 512 + lane * 8) = f;
        }
        bb[i] = b_ih[jb * 16 + nn];
    }
    __syncthreads();

    const int RT = ns * 4;                      // 16-row tiles in this chunk
    for (int rt = blockIdx.x; rt < RT; rt += gridDim.x) {
        {   // stage x rows rt*16 .. rt*16+15 (chunk-local) into A layout
            const int f = 2 * tid, row = f >> 6, k = f & 63;
            float2 v = *(const float2*)(x + ((size_t)(t0 * 64) + rt * 16) * NI + f);
            bf16x2 s; s[0] = (short)f2bf(v.x); s[1] = (short)f2bf(v.y);
            *(bf16x2*)(axs + (k >> 5) * 512 + (((k >> 3) & 3) * 16 + row) * 8 + (k & 7)) = s;
        }
        __syncthreads();
        bf16x8 a0 = *(const bf16x8*)(axs + lane * 8);
        bf16x8 a1 = *(const bf16x8*)(axs + 512 + lane * 8);
        const int tl = rt >> 2, bc = rt & 3;
        #pragma unroll
        for (int i = 0; i < 6; ++i) {
            const int jb = wv + 8 * i;
            f32x4 acc = 0;
            acc = mfma16(a0, *(const bf16x8*)(wihs + (jb * 2 + 0) * 512 + lane * 8), acc);
            acc = mfma16(a1, *(const bf16x8*)(wihs + (jb * 2 + 1) * 512 + lane * 8), acc);
            bf16x4 v;
            #pragma unroll
            for (int m = 0; m < 4; ++m) v[m] = (short)f2bf(acc[m] + bb[i]);
            short* p = xg + ((((size_t)tl * 4 + bc) * 16 + (jb & 15)) * 64 + lane) * 12
                          + (jb >> 4) * 4;
            *(bf16x4*)p = v;
        }
        __syncthreads();   // protect axs before next tile's restage
    }
}

// ============ recurrent kernel ==============================================
// grid 4 x 1024 threads (16 waves). Block bc owns batch rows bc*16..+15.
// Wave wv owns hidden j-block wv (16 units) for all 3 gates.
// r/z W_hh tiles: VGPR frags (64 regs). n-gate W_hh tiles: LDS.
// LDS: wlds 128KB | abuf h-dbuf 16KB | fcred 2KB | oring 8KB  = 157696 B.
__global__ __launch_bounds__(1024, 4) void gru_rec(
        const short* __restrict__ xg,
        const float* __restrict__ w_hh,
        const float* __restrict__ b_hh,
        const float* __restrict__ fc_w,
        const float* __restrict__ fc_b,
        float* __restrict__ out,
        float* __restrict__ hcar,
        int t0, int ns)
{
    __shared__ short wlds[65536];    // 16 jb x 8 chunks x 512 shorts (n-gate)
    __shared__ short abuf[8192];     // h staging, 2 x 8 chunks x 512 shorts
    __shared__ float fcred[512];     // [2][16 waves][16 batch]
    __shared__ float oring[2048];    // [2][64 steps][16 batch]

    const int tid = threadIdx.x, wv = tid >> 6, lane = tid & 63;
    const int nn = lane & 15, q = lane >> 4;
    const int bc = blockIdx.x, bbase = bc * 16;

    // ---- one-time weight staging ----
    bf16x8 wr[8], wz[8];
    #pragma unroll
    for (int c = 0; c < 8; ++c)
        wr[c] = ldfrag(w_hh + (0 * NH + wv * 16 + nn) * NH + c * 32 + q * 8);
    #pragma unroll
    for (int c = 0; c < 8; ++c)
        wz[c] = ldfrag(w_hh + (1 * NH + wv * 16 + nn) * NH + c * 32 + q * 8);
    #pragma unroll
    for (int c = 0; c < 8; ++c) {
        bf16x8 f = ldfrag(w_hh + (2 * NH + wv * 16 + nn) * NH + c * 32 + q * 8);
        *(bf16x8*)(wlds + (wv * 8 + c) * 512 + lane * 8) = f;
    }
    const float bmr = b_hh[0 * NH + wv * 16 + nn];
    const float bmz = b_hh[1 * NH + wv * 16 + nn];
    const float bhn = b_hh[2 * NH + wv * 16 + nn];
    const float fcw = fc_w[wv * 16 + nn];
    const float fcb = fc_b[0];

    // ---- h init (zeros at t0==0, else from carry) ----
    f32x4 hp = 0;
    if (t0 == 0) {
        ((int4*)abuf)[tid] = make_int4(0, 0, 0, 0);   // both buffers zeroed
    } else {
        #pragma unroll
        for (int m = 0; m < 4; ++m)
            hp[m] = hcar[(size_t)(bbase + q * 4 + m) * NH + wv * 16 + nn];
        const int f = tid * 4, b = f >> 8, k0 = f & 255;
        float4 v = *(const float4*)(hcar + (size_t)(bbase + b) * NH + k0);
        bf16x4 s; s[0] = (short)f2bf(v.x); s[1] = (short)f2bf(v.y);
        s[2] = (short)f2bf(v.z); s[3] = (short)f2bf(v.w);
        *(bf16x4*)(abuf + (k0 >> 5) * 512 + (((k0 >> 3) & 3) * 16 + b) * 8 + (k0 & 7)) = s;
    }

    // loop-invariant addresses
    const int j = wv * 16 + nn;
    const int koff = (j >> 5) * 512 + ((j >> 3) & 3) * 128 + (j & 7) + q * 32;
    const short* xgp = xg + ((size_t)(bc * 16 + wv) * 64 + lane) * 12;
    __syncthreads();

    for (int t = 0; t < ns; ++t) {
        const int cur = t & 1, nxt = cur ^ 1;

        // xg for this step (consumed in epilogue; latency hidden under MFMAs)
        int2 gx = *(const int2*)(xgp);
        int2 gz = *(const int2*)(xgp + 4);
        int2 gn = *(const int2*)(xgp + 8);
        xgp += 49152;

        // out flush: once per 64 steps, reads a ring buffer finalized >=1
        // barrier ago; the only global store in the loop.
        if ((t & 63) == 1 && t >= 65) {
            const int s0 = t - 65, buf = (s0 >> 6) & 1;
            out[(size_t)(t0 + s0 + (tid >> 4)) * NB + bbase + (tid & 15)] =
                oring[buf * 1024 + (tid >> 4) * 16 + (tid & 15)];
        }

        f32x4 ar = 0, az = 0, an = 0;
        const short* ab = abuf + cur * 4096;
        #pragma unroll
        for (int c = 0; c < 8; ++c) {
            bf16x8 av = *(const bf16x8*)(ab + c * 512 + lane * 8);
            ar = mfma16(av, wr[c], ar);
            az = mfma16(av, wz[c], az);
            bf16x8 wn = *(const bf16x8*)(wlds + (wv * 8 + c) * 512 + lane * 8);
            an = mfma16(av, wn, an);
        }

        const float xr[4] = { bflo(gx.x), bfhi(gx.x), bflo(gx.y), bfhi(gx.y) };
        const float xz[4] = { bflo(gz.x), bfhi(gz.x), bflo(gz.y), bfhi(gz.y) };
        const float xn[4] = { bflo(gn.x), bfhi(gn.x), bflo(gn.y), bfhi(gn.y) };

        short* hw = abuf + nxt * 4096 + koff;
        f32x4 pf;
        #pragma unroll
        for (int m = 0; m < 4; ++m) {
            float r_ = sigm(ar[m] + bmr + xr[m]);
            float z_ = sigm(az[m] + bmz + xz[m]);
            float n_ = tanh_(fmaf(r_, an[m] + bhn, xn[m]));
            float h_ = n_ + z_ * (hp[m] - n_);
            hp[m] = h_;
            hw[m * 8] = (short)f2bf(h_);
            pf[m] = h_ * fcw;
        }
        // reduce FC partial over the 16 nn-lanes of each quad row
        #pragma unroll
        for (int d = 1; d < 16; d <<= 1) {
            pf[0] += __shfl_xor(pf[0], d);
            pf[1] += __shfl_xor(pf[1], d);
            pf[2] += __shfl_xor(pf[2], d);
            pf[3] += __shfl_xor(pf[3], d);
        }
        if (nn == 0)
            *(f32x4*)(fcred + cur * 256 + wv * 16 + q * 4) = pf;

        // rotating wave finishes step t-1: sum 16 wave-partials -> out ring
        if (t > 0 && wv == (t & 15)) {
            const int s = t - 1, wg = lane >> 4, b = lane & 15;
            const float* fr = fcred + (s & 1) * 256 + b;
            float v = fr[wg * 16] + fr[(wg + 4) * 16] +
                      fr[(wg + 8) * 16] + fr[(wg + 12) * 16];
            v += __shfl_xor(v, 16);
            v += __shfl_xor(v, 32);
            if (lane < 16)
                oring[((s >> 6) & 1) * 1024 + (s & 63) * 16 + lane] = v + fcb;
        }
        __syncthreads();   // single per-step barrier (all LDS slots dbuf'd)
    }

    // ---- tail: finish step ns-1, flush last 64 outputs, write h carry ----
    if (wv == (ns & 15)) {
        const int s = ns - 1, wg = lane >> 4, b = lane & 15;
        const float* fr = fcred + (s & 1) * 256 + b;
        float v = fr[wg * 16] + fr[(wg + 4) * 16] +
                  fr[(wg + 8) * 16] + fr[(wg + 12) * 16];
        v += __shfl_xor(v, 16);
        v += __shfl_xor(v, 32);
        if (lane < 16)
            oring[((s >> 6) & 1) * 1024 + (s & 63) * 16 + lane] = v + fcb;
    }
    __syncthreads();
    {
        const int s0 = ns - 64, buf = (s0 >> 6) & 1;
        out[(size_t)(t0 + s0 + (tid >> 4)) * NB + bbase + (tid & 15)] =
            oring[buf * 1024 + (tid >> 4) * 16 + (tid & 15)];
    }
    #pragma unroll
    for (int m = 0; m < 4; ++m)
        hcar[(size_t)(bbase + q * 4 + m) * NH + wv * 16 + nn] = hp[m];
}

extern "C" void kernel_launch(void* const* d_in, const int* in_sizes, int n_in,
                              void* d_out, int out_size, void* d_ws, size_t ws_size,
                              hipStream_t stream) {
    (void)in_sizes; (void)n_in; (void)out_size;
    const float* x    = (const float*)d_in[0];
    const float* w_ih = (const float*)d_in[1];
    const float* w_hh = (const float*)d_in[2];
    const float* b_ih = (const float*)d_in[3];
    const float* b_hh = (const float*)d_in[4];
    const float* fc_w = (const float*)d_in[5];
    const float* fc_b = (const float*)d_in[6];
    float* out  = (float*)d_out;
    float* hcar = (float*)d_ws;                       // 64 KB h carry
    short* xg   = (short*)((char*)d_ws + 65536);      // xg scratch

    const size_t per_step = (size_t)NB * 3 * NH * 2;  // 98304 B / step
    long avail = (long)ws_size - 65536;
    int spc = 64;
    if (avail >= (long)per_step * 64) {
        spc = (int)((avail / (long)per_step) / 64) * 64;
        if (spc > SEQ) spc = SEQ;
    }
    for (int t0 = 0; t0 < SEQ; t0 += spc) {
        int ns = (SEQ - t0 < spc) ? (SEQ - t0) : spc;
        xg_pre<<<dim3(512), dim3(512), 0, stream>>>(x, w_ih, b_ih, xg, t0, ns);
        gru_rec<<<dim3(4), dim3(1024), 0, stream>>>(xg, w_hh, b_hh, fc_w, fc_b,
                                                    out, hcar, t0, ns);
    }
}

// Round 4
// 6928.866 us; speedup vs baseline: 2.0244x; 1.1497x over previous
//
#include <hip/hip_runtime.h>

#define SEQ  4096
#define NB   64
#define NI   64
#define NH   256

typedef short  bf16x8 __attribute__((ext_vector_type(8)));
typedef short  bf16x4 __attribute__((ext_vector_type(4)));
typedef float  f32x4  __attribute__((ext_vector_type(4)));

__device__ __forceinline__ unsigned short f2bf(float f) {
    union { float f; unsigned u; } v; v.f = f;
    return (unsigned short)((v.u + 0x7fffu + ((v.u >> 16) & 1u)) >> 16);
}
__device__ __forceinline__ float bflo(int p) {
    union { int i; float f; } u; u.i = p << 16; return u.f;
}
__device__ __forceinline__ float bfhi(int p) {
    union { int i; float f; } u; u.i = p & 0xffff0000; return u.f;
}
__device__ __forceinline__ float fast_rcp(float x) { return __builtin_amdgcn_rcpf(x); }
__device__ __forceinline__ float sigm(float x) { return fast_rcp(1.f + __expf(-x)); }
__device__ __forceinline__ float tanh_(float x) {
    x = fminf(15.f, fmaxf(-15.f, x));
    float e = __expf(2.f * x);
    return (e - 1.f) * fast_rcp(e + 1.f);
}
__device__ __forceinline__ f32x4 mfma16(bf16x8 a, bf16x8 b, f32x4 c) {
    return __builtin_amdgcn_mfma_f32_16x16x32_bf16(a, b, c, 0, 0, 0);
}
__device__ __forceinline__ bf16x8 ldfrag(const float* p) {
    float4 a = *(const float4*)p;
    float4 b = *(const float4*)(p + 4);
    bf16x8 r;
    r[0] = (short)f2bf(a.x); r[1] = (short)f2bf(a.y);
    r[2] = (short)f2bf(a.z); r[3] = (short)f2bf(a.w);
    r[4] = (short)f2bf(b.x); r[5] = (short)f2bf(b.y);
    r[6] = (short)f2bf(b.z); r[7] = (short)f2bf(b.w);
    return r;
}

// ============ xg precompute: LDS-free, barrier-free =========================
// Gate-planar output, plane g holds bf16x4 per (tile, jb, lane):
//   xg[g*plane + ((rt*16 + jb)*64 + lane)*4 + m]
// Wave wv = jb; lane (nn,q) reg m = gate value for batch row rt*16 + q*4+m??
// (MFMA D: row = batch = q*4+m, col = j = jb*16+nn.)  b_hh folded for r,z.
__global__ __launch_bounds__(1024) void xg_pre(
        const float* __restrict__ x, const float* __restrict__ w_ih,
        const float* __restrict__ b_ih, const float* __restrict__ b_hh,
        short* __restrict__ xg, size_t plane, int t0, int ns)
{
    const int tid = threadIdx.x, wv = tid >> 6, lane = tid & 63;
    const int nn = lane & 15, q = lane >> 4;
    const int jb = wv;

    bf16x8 w[3][2];
    float bias[3];
    #pragma unroll
    for (int g = 0; g < 3; ++g) {
        const int row = g * NH + jb * 16 + nn;
        w[g][0] = ldfrag(w_ih + row * NI + q * 8);
        w[g][1] = ldfrag(w_ih + row * NI + 32 + q * 8);
        bias[g] = b_ih[row] + (g < 2 ? b_hh[row] : 0.f);
    }

    const int NT = ns * 4;                       // 16-row tiles in chunk
    for (int rt = blockIdx.x; rt < NT; rt += gridDim.x) {
        // A-frag direct from global: lane (nn,q) holds x[row=rt*16+nn][k=c*32+q*8+e]
        const float* xr = x + ((size_t)t0 * NB + (size_t)rt * 16 + nn) * NI + q * 8;
        bf16x8 a0 = ldfrag(xr);
        bf16x8 a1 = ldfrag(xr + 32);
        #pragma unroll
        for (int g = 0; g < 3; ++g) {
            f32x4 acc = {0.f, 0.f, 0.f, 0.f};
            acc = mfma16(a0, w[g][0], acc);
            acc = mfma16(a1, w[g][1], acc);
            bf16x4 v;
            #pragma unroll
            for (int m = 0; m < 4; ++m) v[m] = (short)f2bf(acc[m] + bias[g]);
            *(bf16x4*)(xg + (size_t)g * plane +
                       (((size_t)rt * 16 + jb) * 64 + lane) * 4) = v;
        }
    }
}

// ============ recurrent kernel ==============================================
// grid 4 x 1024 threads (16 waves). Block bc: batch rows bc*16..+15.
// Wave wv: hidden j-block wv (16 units), r/z weights in AGPR, n in LDS.
// FC fused as one extra MFMA on a rotating wave (null-column fc B-frag).
// LDS: wlds 128K | abuf 16K | fcwl 8K | oring 4K = 156 KB.
__global__ __launch_bounds__(1024, 4) void gru_rec(
        const short* __restrict__ xg, size_t plane,
        const float* __restrict__ w_hh,
        const float* __restrict__ b_hh,
        const float* __restrict__ fc_w,
        const float* __restrict__ fc_b,
        float* __restrict__ out,
        float* __restrict__ hcar,
        int t0, int ns)
{
    __shared__ short wlds[65536];    // n-gate W_hh: 16 jb x 8 chunks x 512
    __shared__ short abuf[8192];     // h staging, 2 x 8 chunks x 512
    __shared__ short fcwl[4096];     // fc_w B-frags (col 0 only), 8 x 512
    __shared__ float oring[1024];    // out ring, 2 x 32 steps x 16 batch

    const int tid = threadIdx.x, wv = tid >> 6, lane = tid & 63;
    const int nn = lane & 15, q = lane >> 4;
    const int bc = blockIdx.x, bbase = bc * 16;

    // ---- one-time staging ----
    bf16x8 wr[8], wz[8];
    #pragma unroll
    for (int c = 0; c < 8; ++c)
        wr[c] = ldfrag(w_hh + (0 * NH + wv * 16 + nn) * NH + c * 32 + q * 8);
    #pragma unroll
    for (int c = 0; c < 8; ++c)
        wz[c] = ldfrag(w_hh + (1 * NH + wv * 16 + nn) * NH + c * 32 + q * 8);
    #pragma unroll
    for (int c = 0; c < 8; ++c) {
        bf16x8 f = ldfrag(w_hh + (2 * NH + wv * 16 + nn) * NH + c * 32 + q * 8);
        *(bf16x8*)(wlds + (wv * 8 + c) * 512 + lane * 8) = f;
    }
    if (wv < 8) {                    // fc B-frag: col nn==0 = fc_w, else 0
        bf16x8 f = 0;
        if (nn == 0) f = ldfrag(fc_w + wv * 32 + q * 8);
        *(bf16x8*)(fcwl + wv * 512 + lane * 8) = f;
    }
    const float bhn = b_hh[2 * NH + wv * 16 + nn];
    const float fcb = fc_b[0];

    // ---- h init ----
    f32x4 hp = {0.f, 0.f, 0.f, 0.f};
    if (t0 == 0) {
        ((int4*)abuf)[tid] = make_int4(0, 0, 0, 0);
    } else {
        #pragma unroll
        for (int m = 0; m < 4; ++m)
            hp[m] = hcar[(size_t)(bbase + q * 4 + m) * NH + wv * 16 + nn];
        const int f = tid * 4, b = f >> 8, k0 = f & 255;
        float4 v = *(const float4*)(hcar + (size_t)(bbase + b) * NH + k0);
        bf16x4 s; s[0] = (short)f2bf(v.x); s[1] = (short)f2bf(v.y);
        s[2] = (short)f2bf(v.z); s[3] = (short)f2bf(v.w);
        *(bf16x4*)(abuf + (k0 >> 5) * 512 + (((k0 >> 3) & 3) * 16 + b) * 8 + (k0 & 7)) = s;
    }

    const int j = wv * 16 + nn;
    const int koff = (j >> 5) * 512 + ((j >> 3) & 3) * 128 + (j & 7) + q * 32;
    const short* xgp = xg + ((size_t)(bc * 16 + wv) * 64 + lane) * 4;
    __syncthreads();

    for (int t = 0; t < ns; ++t) {
        const int cur = t & 1, nxt = cur ^ 1;

        int2 gx = *(const int2*)(xgp);
        int2 gz = *(const int2*)(xgp + plane);
        int2 gn = *(const int2*)(xgp + 2 * plane);
        xgp += 16384;

        // out flush, once per 32 steps (slots all >=1 barrier old)
        if ((t & 31) == 1 && t >= 33 && tid < 512) {
            const int s0 = t - 33;
            out[((size_t)(t0 + s0 + (tid >> 4))) * NB + bbase + (tid & 15)] =
                oring[(((s0 >> 5) & 1) << 9) + (tid >> 4) * 16 + (tid & 15)];
        }

        const bool isfc = (t > 0) && (wv == (t & 15));
        f32x4 ar = {0.f,0.f,0.f,0.f}, az = {0.f,0.f,0.f,0.f};
        f32x4 an = {0.f,0.f,0.f,0.f}, afc = {0.f,0.f,0.f,0.f};
        const short* ab = abuf + cur * 4096;
        #pragma unroll
        for (int c = 0; c < 8; ++c) {
            bf16x8 av = *(const bf16x8*)(ab + c * 512 + lane * 8);
            ar = mfma16(av, wr[c], ar);
            az = mfma16(av, wz[c], az);
            bf16x8 wnf = *(const bf16x8*)(wlds + (wv * 8 + c) * 512 + lane * 8);
            an = mfma16(av, wnf, an);
            if (isfc) {   // rotating wave: FC(h_{t-1}) rides on the same av
                bf16x8 ff = *(const bf16x8*)(fcwl + c * 512 + lane * 8);
                afc = mfma16(av, ff, afc);
            }
        }
        if (isfc && nn == 0) {
            const int s = t - 1;
            f32x4 v;
            #pragma unroll
            for (int m = 0; m < 4; ++m) v[m] = afc[m] + fcb;
            *(f32x4*)(oring + (((s >> 5) & 1) << 9) + ((s & 31) << 4) + q * 4) = v;
        }

        const float xr4[4] = { bflo(gx.x), bfhi(gx.x), bflo(gx.y), bfhi(gx.y) };
        const float xz4[4] = { bflo(gz.x), bfhi(gz.x), bflo(gz.y), bfhi(gz.y) };
        const float xn4[4] = { bflo(gn.x), bfhi(gn.x), bflo(gn.y), bfhi(gn.y) };

        short* hw = abuf + nxt * 4096 + koff;
        #pragma unroll
        for (int m = 0; m < 4; ++m) {
            float r_ = sigm(ar[m] + xr4[m]);          // b_hh folded upstream
            float z_ = sigm(az[m] + xz4[m]);
            float n_ = tanh_(fmaf(r_, an[m] + bhn, xn4[m]));
            float h_ = n_ + z_ * (hp[m] - n_);
            hp[m] = h_;
            hw[m * 8] = (short)f2bf(h_);
        }
        __syncthreads();   // single per-step barrier
    }

    // ---- tail: FC for step ns-1, flush last 32, h carry ----
    if (wv == 0) {
        const short* ab = abuf + (ns & 1) * 4096;
        f32x4 afc = {0.f, 0.f, 0.f, 0.f};
        #pragma unroll
        for (int c = 0; c < 8; ++c)
            afc = mfma16(*(const bf16x8*)(ab + c * 512 + lane * 8),
                         *(const bf16x8*)(fcwl + c * 512 + lane * 8), afc);
        if (nn == 0) {
            const int s = ns - 1;
            f32x4 v;
            #pragma unroll
            for (int m = 0; m < 4; ++m) v[m] = afc[m] + fcb;
            *(f32x4*)(oring + (((s >> 5) & 1) << 9) + ((s & 31) << 4) + q * 4) = v;
        }
    }
    __syncthreads();
    if (tid < 512) {
        const int s0 = ns - 32;
        out[((size_t)(t0 + s0 + (tid >> 4))) * NB + bbase + (tid & 15)] =
            oring[(((s0 >> 5) & 1) << 9) + (tid >> 4) * 16 + (tid & 15)];
    }
    #pragma unroll
    for (int m = 0; m < 4; ++m)
        hcar[(size_t)(bbase + q * 4 + m) * NH + wv * 16 + nn] = hp[m];
}

extern "C" void kernel_launch(void* const* d_in, const int* in_sizes, int n_in,
                              void* d_out, int out_size, void* d_ws, size_t ws_size,
                              hipStream_t stream) {
    (void)in_sizes; (void)n_in; (void)out_size;
    const float* x    = (const float*)d_in[0];
    const float* w_ih = (const float*)d_in[1];
    const float* w_hh = (const float*)d_in[2];
    const float* b_ih = (const float*)d_in[3];
    const float* b_hh = (const float*)d_in[4];
    const float* fc_w = (const float*)d_in[5];
    const float* fc_b = (const float*)d_in[6];
    float* out  = (float*)d_out;
    float* hcar = (float*)d_ws;                       // 64 KB h carry
    short* xg   = (short*)((char*)d_ws + 65536);      // 3 gate planes

    const size_t per_step = (size_t)NB * 3 * NH * 2;  // 98304 B / step
    long avail = (long)ws_size - 65536;
    int spc = 64;
    if (avail >= (long)per_step * 64) {
        spc = (int)((avail / (long)per_step) / 64) * 64;
        if (spc > SEQ) spc = SEQ;
    }
    for (int t0 = 0; t0 < SEQ; t0 += spc) {
        int ns = (SEQ - t0 < spc) ? (SEQ - t0) : spc;
        size_t plane = (size_t)spc * 16384;           // shorts per gate plane
        xg_pre<<<dim3(2048), dim3(1024), 0, stream>>>(x, w_ih, b_ih, b_hh,
                                                      xg, plane, t0, ns);
        gru_rec<<<dim3(4), dim3(1024), 0, stream>>>(xg, plane, w_hh, b_hh,
                                                    fc_w, fc_b, out, hcar,
                                                    t0, ns);
    }
}